// Round 8
// baseline (219.370 us; speedup 1.0000x reference)
//
#include <hip/hip_runtime.h>

// SSIM loss: pred/target [16,3,512,512] fp32, 11x11 gaussian (sigma=1.5),
// zero-padded SAME depthwise conv, output scalar 1 - mean(ssim_map).
//
// v7b: v6 algebra (u=p+t, v=p-t -> 4 convs: cu,cv,cu2,cv2) + bf16 LDS
// planes: hsum float4 packed as 4xbf16 in one uint2 (manual RNE pack —
// __floats2bfloat162_rn does not exist in ROCm 7.2). LDS 39.4->19.5 KB
// -> 8 blocks/CU -> 32 waves/CU (was 16). Numerics: hsums O(1), bf16 RNE
// err ~0.4% per value, averaged over 12.58M px with ~zero bias -> far
// under the 1.98e-2 threshold (loss ~0.988, mean ssim ~0.012).

#define IMG 512
#define NCHAN 48
#define TW 32
#define TH 64
#define HR (TH + 10)   // 74 hsum rows per tile
#define PST 33         // padded plane row stride (uint2 elems)

constexpr double RW1 = 0.8007374029168082;
constexpr double RW2 = 0.4111122905071876;
constexpr double RW3 = 0.1353352832366127;
constexpr double RW4 = 0.0285655007845504;
constexpr double RW5 = 0.0038659201394728;
constexpr double RSUM = 1.0 + 2.0 * (RW1 + RW2 + RW3 + RW4 + RW5);
constexpr float GW[11] = {
    (float)(RW5 / RSUM), (float)(RW4 / RSUM), (float)(RW3 / RSUM),
    (float)(RW2 / RSUM), (float)(RW1 / RSUM), (float)(1.0 / RSUM),
    (float)(RW1 / RSUM), (float)(RW2 / RSUM), (float)(RW3 / RSUM),
    (float)(RW4 / RSUM), (float)(RW5 / RSUM)};

// Manual bf16 round-to-nearest-even (inputs are always finite here).
__device__ __forceinline__ unsigned bf16_rne(float x) {
  const unsigned u = __float_as_uint(x);
  return (u + 0x7fffu + ((u >> 16) & 1u)) >> 16;
}
__device__ __forceinline__ unsigned pk_bf16(float a, float b) {
  return bf16_rne(a) | (bf16_rne(b) << 16);
}
__device__ __forceinline__ float bf_lo(unsigned u) {
  return __uint_as_float(u << 16);
}
__device__ __forceinline__ float bf_hi(unsigned u) {
  return __uint_as_float(u & 0xffff0000u);
}

// ---- Phase B building blocks: item j in [0, HR*8) = 4 hsum outputs.
template <bool CHECKED>
__device__ __forceinline__ void hload(const float* __restrict__ P,
                                      const float* __restrict__ T, int r0t,
                                      int c0, int j, float4* vp, float4* vt) {
  const int g = j & 7;
  const int h = j >> 3;
  const int gy = r0t - 5 + h;
  const int gx0 = c0 + g * 4 - 8;  // aligned 20-float window (mult of 4)
  if (CHECKED) {
    const bool rowok = (gy >= 0) && (gy < IMG);
    const float* __restrict__ Prow = P + (size_t)gy * IMG;
    const float* __restrict__ Trow = T + (size_t)gy * IMG;
#pragma unroll
    for (int q = 0; q < 5; ++q) {
      const int gx = gx0 + q * 4;
      vp[q] = make_float4(0.f, 0.f, 0.f, 0.f);
      vt[q] = vp[q];
      // gx is a multiple of 4 and IMG%4==0: float4 is all-in or all-out.
      if (rowok && gx >= 0 && gx < IMG) {
        vp[q] = *(const float4*)(Prow + gx);
        vt[q] = *(const float4*)(Trow + gx);
      }
    }
  } else {
    const float* __restrict__ Prow = P + (size_t)gy * IMG + gx0;
    const float* __restrict__ Trow = T + (size_t)gy * IMG + gx0;
#pragma unroll
    for (int q = 0; q < 5; ++q) {
      vp[q] = *(const float4*)(Prow + q * 4);
      vt[q] = *(const float4*)(Trow + q * 4);
    }
  }
}

__device__ __forceinline__ void hcompute(int j, const float4* vp,
                                         const float4* vt, uint2 (*hs)[PST]) {
  const int g = j & 7;
  const int h = j >> 3;
  float2 uv[20];  // (u, v) = (p+t, p-t)
#pragma unroll
  for (int q = 0; q < 5; ++q) {
    const float4 p4 = vp[q], t4 = vt[q];
    uv[q * 4 + 0] = make_float2(p4.x + t4.x, p4.x - t4.x);
    uv[q * 4 + 1] = make_float2(p4.y + t4.y, p4.y - t4.y);
    uv[q * 4 + 2] = make_float2(p4.z + t4.z, p4.z - t4.z);
    uv[q * 4 + 3] = make_float2(p4.w + t4.w, p4.w - t4.w);
  }
  uint2 outp[4];
#pragma unroll
  for (int o = 0; o < 4; ++o) {
    float cu = 0.f, cv = 0.f, cu2 = 0.f, cv2 = 0.f;
#pragma unroll
    for (int k = 0; k < 11; ++k) {
      const float2 e = uv[3 + o + k];
      const float wu = GW[k] * e.x;
      const float wv = GW[k] * e.y;
      cu += wu;
      cv += wv;
      cu2 = fmaf(wu, e.x, cu2);
      cv2 = fmaf(wv, e.y, cv2);
    }
    outp[o].x = pk_bf16(cu, cv);
    outp[o].y = pk_bf16(cu2, cv2);
  }
  // 16B contiguous stores (g*4 even -> 16B-aligned within the plane row)
  *(uint4*)&hs[h][g * 4] = make_uint4(outp[0].x, outp[0].y, outp[1].x,
                                      outp[1].y);
  *(uint4*)&hs[h][g * 4 + 2] = make_uint4(outp[2].x, outp[2].y, outp[3].x,
                                          outp[3].y);
}

template <bool CHECKED>
__device__ __forceinline__ void phase_b(const float* __restrict__ P,
                                        const float* __restrict__ T, int r0t,
                                        int c0, int tid, uint2 (*hs)[PST]) {
  // HR*8 = 592 items: tid and tid+256 unconditional (loads hoisted so both
  // items' 20 b128 loads are in flight together), tid+512 for tid<80.
  float4 ap[5], at[5], bp[5], bt[5];
  hload<CHECKED>(P, T, r0t, c0, tid, ap, at);
  hload<CHECKED>(P, T, r0t, c0, tid + 256, bp, bt);
  hcompute(tid, ap, at, hs);
  hcompute(tid + 256, bp, bt, hs);
  if (tid < HR * 8 - 512) {
    hload<CHECKED>(P, T, r0t, c0, tid + 512, ap, at);
    hcompute(tid + 512, ap, at, hs);
  }
}

__global__ __launch_bounds__(256, 8) void ssim_main(
    const float* __restrict__ pred, const float* __restrict__ tgt,
    double* __restrict__ ws) {
  __shared__ uint2 hs[HR][PST];  // 4xbf16: (cu, cv | cu2, cv2)
  __shared__ float wsum[4];

  const int tid = threadIdx.x;
  const int c0 = blockIdx.x * TW;
  const int r0t = blockIdx.y * TH;
  const int nc = blockIdx.z;
  const size_t base = (size_t)nc * IMG * IMG;
  const float* __restrict__ P = pred + base;
  const float* __restrict__ T = tgt + base;

  const bool interior =
      (c0 != 0) && (c0 != IMG - TW) && (r0t != 0) && (r0t != IMG - TH);
  if (interior)
    phase_b<false>(P, T, r0t, c0, tid, hs);
  else
    phase_b<true>(P, T, r0t, c0, tid, hs);
  __syncthreads();

  // ---- Phase C: vertical windowed sums, row-streaming, 8 outputs/thread
  float lsum = 0.f;
  {
    const int x = tid & (TW - 1);
    const int r0 = (tid >> 5) * 8;  // 8 strips * 8 rows = 64
    float2 amu[8], asq[8];
#pragma unroll
    for (int o = 0; o < 8; ++o) {
      amu[o] = make_float2(0.f, 0.f);
      asq[o] = make_float2(0.f, 0.f);
    }
#pragma unroll
    for (int j = 0; j < 18; ++j) {
      const uint2 hv = hs[r0 + j][x];
      const float hcu = bf_lo(hv.x), hcv = bf_hi(hv.x);
      const float hc2u = bf_lo(hv.y), hc2v = bf_hi(hv.y);
#pragma unroll
      for (int o = 0; o < 8; ++o) {
        const int k = j - o;
        if (k >= 0 && k < 11) {
          const float w = GW[k];
          amu[o].x = fmaf(w, hcu, amu[o].x);
          amu[o].y = fmaf(w, hcv, amu[o].y);
          asq[o].x = fmaf(w, hc2u, asq[o].x);
          asq[o].y = fmaf(w, hc2v, asq[o].y);
        }
      }
    }
#pragma unroll
    for (int o = 0; o < 8; ++o) {
      const float cu = amu[o].x, cv = amu[o].y;
      const float cu2 = asq[o].x, cv2 = asq[o].y;
      const float cusq = cu * cu, cvsq = cv * cv;
      const float mu12 = 0.25f * (cusq - cvsq);       // mu1*mu2
      const float musq = 0.5f * (cusq + cvsq);        // mu1^2+mu2^2
      const float s12 = 0.25f * (cu2 - cv2);          // conv(p*t)
      const float ssq = 0.5f * (cu2 + cv2);           // s11+s22
      const float num = (2.f * mu12 + 1e-4f) * (2.f * (s12 - mu12) + 9e-4f);
      const float den = (musq + 1e-4f) * (ssq - musq + 9e-4f);
      lsum += num * __builtin_amdgcn_rcpf(den);
    }
  }

  // ---- Block reduce, one f64 atomic per block into per-channel bucket
#pragma unroll
  for (int off = 32; off > 0; off >>= 1) lsum += __shfl_down(lsum, off, 64);
  if ((tid & 63) == 0) wsum[tid >> 6] = lsum;
  __syncthreads();
  if (tid == 0) {
    const float bsum = wsum[0] + wsum[1] + wsum[2] + wsum[3];
    unsafeAtomicAdd(&ws[nc], (double)bsum);
  }
}

__global__ void ssim_fin(const double* __restrict__ ws,
                         float* __restrict__ out) {
  const int l = threadIdx.x;
  double v = (l < NCHAN) ? ws[l] : 0.0;
#pragma unroll
  for (int off = 32; off > 0; off >>= 1) v += __shfl_down(v, off, 64);
  if (l == 0) out[0] = (float)(1.0 - v / (double)(IMG * IMG * NCHAN));
}

extern "C" void kernel_launch(void* const* d_in, const int* in_sizes, int n_in,
                              void* d_out, int out_size, void* d_ws,
                              size_t ws_size, hipStream_t stream) {
  const float* pred = (const float*)d_in[0];
  const float* tgt = (const float*)d_in[1];
  double* ws = (double*)d_ws;

  (void)hipMemsetAsync(d_ws, 0, NCHAN * sizeof(double), stream);
  dim3 grid(IMG / TW, IMG / TH, NCHAN);
  ssim_main<<<grid, 256, 0, stream>>>(pred, tgt, ws);
  ssim_fin<<<1, 64, 0, stream>>>(ws, (float*)d_out);
}

// Round 9
// 175.671 us; speedup vs baseline: 1.2488x; 1.2488x over previous
//
#include <hip/hip_runtime.h>

// SSIM loss: pred/target [16,3,512,512] fp32, 11x11 gaussian (sigma=1.5),
// zero-padded SAME depthwise conv, output scalar 1 - mean(ssim_map).
//
// v8: v7b (u/v algebra + bf16 LDS planes, 19.97 KB) with __launch_bounds__
// (256,6): VGPR cap 84. R8's (256,8) capped VGPR at 64 -> allocator hit 32
// and spilled phase B's register window to scratch (WRITE_SIZE 167 MB,
// FETCH +134 MB) -> 128 us. v6 needed 52 VGPRs; 84 leaves headroom.
// 6 blocks/CU = 24 waves/CU (1.5x v6's 16).

#define IMG 512
#define NCHAN 48
#define TW 32
#define TH 64
#define HR (TH + 10)   // 74 hsum rows per tile
#define PST 33         // padded plane row stride (uint2 elems)

constexpr double RW1 = 0.8007374029168082;
constexpr double RW2 = 0.4111122905071876;
constexpr double RW3 = 0.1353352832366127;
constexpr double RW4 = 0.0285655007845504;
constexpr double RW5 = 0.0038659201394728;
constexpr double RSUM = 1.0 + 2.0 * (RW1 + RW2 + RW3 + RW4 + RW5);
constexpr float GW[11] = {
    (float)(RW5 / RSUM), (float)(RW4 / RSUM), (float)(RW3 / RSUM),
    (float)(RW2 / RSUM), (float)(RW1 / RSUM), (float)(1.0 / RSUM),
    (float)(RW1 / RSUM), (float)(RW2 / RSUM), (float)(RW3 / RSUM),
    (float)(RW4 / RSUM), (float)(RW5 / RSUM)};

// Manual bf16 round-to-nearest-even (inputs are always finite here).
__device__ __forceinline__ unsigned bf16_rne(float x) {
  const unsigned u = __float_as_uint(x);
  return (u + 0x7fffu + ((u >> 16) & 1u)) >> 16;
}
__device__ __forceinline__ unsigned pk_bf16(float a, float b) {
  return bf16_rne(a) | (bf16_rne(b) << 16);
}
__device__ __forceinline__ float bf_lo(unsigned u) {
  return __uint_as_float(u << 16);
}
__device__ __forceinline__ float bf_hi(unsigned u) {
  return __uint_as_float(u & 0xffff0000u);
}

// ---- Phase B building blocks: item j in [0, HR*8) = 4 hsum outputs.
template <bool CHECKED>
__device__ __forceinline__ void hload(const float* __restrict__ P,
                                      const float* __restrict__ T, int r0t,
                                      int c0, int j, float4* vp, float4* vt) {
  const int g = j & 7;
  const int h = j >> 3;
  const int gy = r0t - 5 + h;
  const int gx0 = c0 + g * 4 - 8;  // aligned 20-float window (mult of 4)
  if (CHECKED) {
    const bool rowok = (gy >= 0) && (gy < IMG);
    const float* __restrict__ Prow = P + (size_t)gy * IMG;
    const float* __restrict__ Trow = T + (size_t)gy * IMG;
#pragma unroll
    for (int q = 0; q < 5; ++q) {
      const int gx = gx0 + q * 4;
      vp[q] = make_float4(0.f, 0.f, 0.f, 0.f);
      vt[q] = vp[q];
      // gx is a multiple of 4 and IMG%4==0: float4 is all-in or all-out.
      if (rowok && gx >= 0 && gx < IMG) {
        vp[q] = *(const float4*)(Prow + gx);
        vt[q] = *(const float4*)(Trow + gx);
      }
    }
  } else {
    const float* __restrict__ Prow = P + (size_t)gy * IMG + gx0;
    const float* __restrict__ Trow = T + (size_t)gy * IMG + gx0;
#pragma unroll
    for (int q = 0; q < 5; ++q) {
      vp[q] = *(const float4*)(Prow + q * 4);
      vt[q] = *(const float4*)(Trow + q * 4);
    }
  }
}

__device__ __forceinline__ void hcompute(int j, const float4* vp,
                                         const float4* vt, uint2 (*hs)[PST]) {
  const int g = j & 7;
  const int h = j >> 3;
  float2 uv[20];  // (u, v) = (p+t, p-t)
#pragma unroll
  for (int q = 0; q < 5; ++q) {
    const float4 p4 = vp[q], t4 = vt[q];
    uv[q * 4 + 0] = make_float2(p4.x + t4.x, p4.x - t4.x);
    uv[q * 4 + 1] = make_float2(p4.y + t4.y, p4.y - t4.y);
    uv[q * 4 + 2] = make_float2(p4.z + t4.z, p4.z - t4.z);
    uv[q * 4 + 3] = make_float2(p4.w + t4.w, p4.w - t4.w);
  }
  uint2 outp[4];
#pragma unroll
  for (int o = 0; o < 4; ++o) {
    float cu = 0.f, cv = 0.f, cu2 = 0.f, cv2 = 0.f;
#pragma unroll
    for (int k = 0; k < 11; ++k) {
      const float2 e = uv[3 + o + k];
      const float wu = GW[k] * e.x;
      const float wv = GW[k] * e.y;
      cu += wu;
      cv += wv;
      cu2 = fmaf(wu, e.x, cu2);
      cv2 = fmaf(wv, e.y, cv2);
    }
    outp[o].x = pk_bf16(cu, cv);
    outp[o].y = pk_bf16(cu2, cv2);
  }
  // 16B contiguous stores (g*4 even -> 16B-aligned within the plane row)
  *(uint4*)&hs[h][g * 4] = make_uint4(outp[0].x, outp[0].y, outp[1].x,
                                      outp[1].y);
  *(uint4*)&hs[h][g * 4 + 2] = make_uint4(outp[2].x, outp[2].y, outp[3].x,
                                          outp[3].y);
}

template <bool CHECKED>
__device__ __forceinline__ void phase_b(const float* __restrict__ P,
                                        const float* __restrict__ T, int r0t,
                                        int c0, int tid, uint2 (*hs)[PST]) {
  // HR*8 = 592 items: tid and tid+256 unconditional (loads hoisted so both
  // items' 20 b128 loads are in flight together), tid+512 for tid<80.
  float4 ap[5], at[5], bp[5], bt[5];
  hload<CHECKED>(P, T, r0t, c0, tid, ap, at);
  hload<CHECKED>(P, T, r0t, c0, tid + 256, bp, bt);
  hcompute(tid, ap, at, hs);
  hcompute(tid + 256, bp, bt, hs);
  if (tid < HR * 8 - 512) {
    hload<CHECKED>(P, T, r0t, c0, tid + 512, ap, at);
    hcompute(tid + 512, ap, at, hs);
  }
}

__global__ __launch_bounds__(256, 6) void ssim_main(
    const float* __restrict__ pred, const float* __restrict__ tgt,
    double* __restrict__ ws) {
  __shared__ uint2 hs[HR][PST];  // 4xbf16: (cu, cv | cu2, cv2)
  __shared__ float wsum[4];

  const int tid = threadIdx.x;
  const int c0 = blockIdx.x * TW;
  const int r0t = blockIdx.y * TH;
  const int nc = blockIdx.z;
  const size_t base = (size_t)nc * IMG * IMG;
  const float* __restrict__ P = pred + base;
  const float* __restrict__ T = tgt + base;

  const bool interior =
      (c0 != 0) && (c0 != IMG - TW) && (r0t != 0) && (r0t != IMG - TH);
  if (interior)
    phase_b<false>(P, T, r0t, c0, tid, hs);
  else
    phase_b<true>(P, T, r0t, c0, tid, hs);
  __syncthreads();

  // ---- Phase C: vertical windowed sums, row-streaming, 8 outputs/thread
  float lsum = 0.f;
  {
    const int x = tid & (TW - 1);
    const int r0 = (tid >> 5) * 8;  // 8 strips * 8 rows = 64
    float2 amu[8], asq[8];
#pragma unroll
    for (int o = 0; o < 8; ++o) {
      amu[o] = make_float2(0.f, 0.f);
      asq[o] = make_float2(0.f, 0.f);
    }
#pragma unroll
    for (int j = 0; j < 18; ++j) {
      const uint2 hv = hs[r0 + j][x];
      const float hcu = bf_lo(hv.x), hcv = bf_hi(hv.x);
      const float hc2u = bf_lo(hv.y), hc2v = bf_hi(hv.y);
#pragma unroll
      for (int o = 0; o < 8; ++o) {
        const int k = j - o;
        if (k >= 0 && k < 11) {
          const float w = GW[k];
          amu[o].x = fmaf(w, hcu, amu[o].x);
          amu[o].y = fmaf(w, hcv, amu[o].y);
          asq[o].x = fmaf(w, hc2u, asq[o].x);
          asq[o].y = fmaf(w, hc2v, asq[o].y);
        }
      }
    }
#pragma unroll
    for (int o = 0; o < 8; ++o) {
      const float cu = amu[o].x, cv = amu[o].y;
      const float cu2 = asq[o].x, cv2 = asq[o].y;
      const float cusq = cu * cu, cvsq = cv * cv;
      const float mu12 = 0.25f * (cusq - cvsq);       // mu1*mu2
      const float musq = 0.5f * (cusq + cvsq);        // mu1^2+mu2^2
      const float s12 = 0.25f * (cu2 - cv2);          // conv(p*t)
      const float ssq = 0.5f * (cu2 + cv2);           // s11+s22
      const float num = (2.f * mu12 + 1e-4f) * (2.f * (s12 - mu12) + 9e-4f);
      const float den = (musq + 1e-4f) * (ssq - musq + 9e-4f);
      lsum += num * __builtin_amdgcn_rcpf(den);
    }
  }

  // ---- Block reduce, one f64 atomic per block into per-channel bucket
#pragma unroll
  for (int off = 32; off > 0; off >>= 1) lsum += __shfl_down(lsum, off, 64);
  if ((tid & 63) == 0) wsum[tid >> 6] = lsum;
  __syncthreads();
  if (tid == 0) {
    const float bsum = wsum[0] + wsum[1] + wsum[2] + wsum[3];
    unsafeAtomicAdd(&ws[nc], (double)bsum);
  }
}

__global__ void ssim_fin(const double* __restrict__ ws,
                         float* __restrict__ out) {
  const int l = threadIdx.x;
  double v = (l < NCHAN) ? ws[l] : 0.0;
#pragma unroll
  for (int off = 32; off > 0; off >>= 1) v += __shfl_down(v, off, 64);
  if (l == 0) out[0] = (float)(1.0 - v / (double)(IMG * IMG * NCHAN));
}

extern "C" void kernel_launch(void* const* d_in, const int* in_sizes, int n_in,
                              void* d_out, int out_size, void* d_ws,
                              size_t ws_size, hipStream_t stream) {
  const float* pred = (const float*)d_in[0];
  const float* tgt = (const float*)d_in[1];
  double* ws = (double*)d_ws;

  (void)hipMemsetAsync(d_ws, 0, NCHAN * sizeof(double), stream);
  dim3 grid(IMG / TW, IMG / TH, NCHAN);
  ssim_main<<<grid, 256, 0, stream>>>(pred, tgt, ws);
  ssim_fin<<<1, 64, 0, stream>>>(ws, (float*)d_out);
}

// Round 10
// 164.742 us; speedup vs baseline: 1.3316x; 1.0663x over previous
//
#include <hip/hip_runtime.h>

// SSIM loss: pred/target [16,3,512,512] fp32, 11x11 gaussian (sigma=1.5),
// zero-padded SAME depthwise conv, output scalar 1 - mean(ssim_map).
//
// v9: v7b (u/v algebra + bf16 LDS planes, 19.97 KB) with NO min-waves
// launch bound. Evidence R8/R9: any VGPR cap below the natural ~52-reg
// footprint makes the allocator snap to a lower bucket WITH spills
// (cap 64 -> 32 regs + 167 MB scratch; cap 80 -> 40 regs + 38 MB).
// Natural allocation (v6: 52 regs, zero spill) + 19.97 KB LDS gives
// min(8 blocks by LDS, ~8 waves/SIMD by VGPR) = 24-32 waves/CU for free.

#define IMG 512
#define NCHAN 48
#define TW 32
#define TH 64
#define HR (TH + 10)   // 74 hsum rows per tile
#define PST 33         // padded plane row stride (uint2 elems)

constexpr double RW1 = 0.8007374029168082;
constexpr double RW2 = 0.4111122905071876;
constexpr double RW3 = 0.1353352832366127;
constexpr double RW4 = 0.0285655007845504;
constexpr double RW5 = 0.0038659201394728;
constexpr double RSUM = 1.0 + 2.0 * (RW1 + RW2 + RW3 + RW4 + RW5);
constexpr float GW[11] = {
    (float)(RW5 / RSUM), (float)(RW4 / RSUM), (float)(RW3 / RSUM),
    (float)(RW2 / RSUM), (float)(RW1 / RSUM), (float)(1.0 / RSUM),
    (float)(RW1 / RSUM), (float)(RW2 / RSUM), (float)(RW3 / RSUM),
    (float)(RW4 / RSUM), (float)(RW5 / RSUM)};

// Manual bf16 round-to-nearest-even (inputs are always finite here).
__device__ __forceinline__ unsigned bf16_rne(float x) {
  const unsigned u = __float_as_uint(x);
  return (u + 0x7fffu + ((u >> 16) & 1u)) >> 16;
}
__device__ __forceinline__ unsigned pk_bf16(float a, float b) {
  return bf16_rne(a) | (bf16_rne(b) << 16);
}
__device__ __forceinline__ float bf_lo(unsigned u) {
  return __uint_as_float(u << 16);
}
__device__ __forceinline__ float bf_hi(unsigned u) {
  return __uint_as_float(u & 0xffff0000u);
}

// ---- Phase B building blocks: item j in [0, HR*8) = 4 hsum outputs.
template <bool CHECKED>
__device__ __forceinline__ void hload(const float* __restrict__ P,
                                      const float* __restrict__ T, int r0t,
                                      int c0, int j, float4* vp, float4* vt) {
  const int g = j & 7;
  const int h = j >> 3;
  const int gy = r0t - 5 + h;
  const int gx0 = c0 + g * 4 - 8;  // aligned 20-float window (mult of 4)
  if (CHECKED) {
    const bool rowok = (gy >= 0) && (gy < IMG);
    const float* __restrict__ Prow = P + (size_t)gy * IMG;
    const float* __restrict__ Trow = T + (size_t)gy * IMG;
#pragma unroll
    for (int q = 0; q < 5; ++q) {
      const int gx = gx0 + q * 4;
      vp[q] = make_float4(0.f, 0.f, 0.f, 0.f);
      vt[q] = vp[q];
      // gx is a multiple of 4 and IMG%4==0: float4 is all-in or all-out.
      if (rowok && gx >= 0 && gx < IMG) {
        vp[q] = *(const float4*)(Prow + gx);
        vt[q] = *(const float4*)(Trow + gx);
      }
    }
  } else {
    const float* __restrict__ Prow = P + (size_t)gy * IMG + gx0;
    const float* __restrict__ Trow = T + (size_t)gy * IMG + gx0;
#pragma unroll
    for (int q = 0; q < 5; ++q) {
      vp[q] = *(const float4*)(Prow + q * 4);
      vt[q] = *(const float4*)(Trow + q * 4);
    }
  }
}

__device__ __forceinline__ void hcompute(int j, const float4* vp,
                                         const float4* vt, uint2 (*hs)[PST]) {
  const int g = j & 7;
  const int h = j >> 3;
  float2 uv[20];  // (u, v) = (p+t, p-t)
#pragma unroll
  for (int q = 0; q < 5; ++q) {
    const float4 p4 = vp[q], t4 = vt[q];
    uv[q * 4 + 0] = make_float2(p4.x + t4.x, p4.x - t4.x);
    uv[q * 4 + 1] = make_float2(p4.y + t4.y, p4.y - t4.y);
    uv[q * 4 + 2] = make_float2(p4.z + t4.z, p4.z - t4.z);
    uv[q * 4 + 3] = make_float2(p4.w + t4.w, p4.w - t4.w);
  }
  uint2 outp[4];
#pragma unroll
  for (int o = 0; o < 4; ++o) {
    float cu = 0.f, cv = 0.f, cu2 = 0.f, cv2 = 0.f;
#pragma unroll
    for (int k = 0; k < 11; ++k) {
      const float2 e = uv[3 + o + k];
      const float wu = GW[k] * e.x;
      const float wv = GW[k] * e.y;
      cu += wu;
      cv += wv;
      cu2 = fmaf(wu, e.x, cu2);
      cv2 = fmaf(wv, e.y, cv2);
    }
    outp[o].x = pk_bf16(cu, cv);
    outp[o].y = pk_bf16(cu2, cv2);
  }
  // 16B contiguous stores (g*4 even -> 16B-aligned within the plane row)
  *(uint4*)&hs[h][g * 4] = make_uint4(outp[0].x, outp[0].y, outp[1].x,
                                      outp[1].y);
  *(uint4*)&hs[h][g * 4 + 2] = make_uint4(outp[2].x, outp[2].y, outp[3].x,
                                          outp[3].y);
}

template <bool CHECKED>
__device__ __forceinline__ void phase_b(const float* __restrict__ P,
                                        const float* __restrict__ T, int r0t,
                                        int c0, int tid, uint2 (*hs)[PST]) {
  // HR*8 = 592 items: tid and tid+256 unconditional (loads hoisted so both
  // items' 20 b128 loads are in flight together), tid+512 for tid<80.
  float4 ap[5], at[5], bp[5], bt[5];
  hload<CHECKED>(P, T, r0t, c0, tid, ap, at);
  hload<CHECKED>(P, T, r0t, c0, tid + 256, bp, bt);
  hcompute(tid, ap, at, hs);
  hcompute(tid + 256, bp, bt, hs);
  if (tid < HR * 8 - 512) {
    hload<CHECKED>(P, T, r0t, c0, tid + 512, ap, at);
    hcompute(tid + 512, ap, at, hs);
  }
}

__global__ __launch_bounds__(256) void ssim_main(
    const float* __restrict__ pred, const float* __restrict__ tgt,
    double* __restrict__ ws) {
  __shared__ uint2 hs[HR][PST];  // 4xbf16: (cu, cv | cu2, cv2)
  __shared__ float wsum[4];

  const int tid = threadIdx.x;
  const int c0 = blockIdx.x * TW;
  const int r0t = blockIdx.y * TH;
  const int nc = blockIdx.z;
  const size_t base = (size_t)nc * IMG * IMG;
  const float* __restrict__ P = pred + base;
  const float* __restrict__ T = tgt + base;

  const bool interior =
      (c0 != 0) && (c0 != IMG - TW) && (r0t != 0) && (r0t != IMG - TH);
  if (interior)
    phase_b<false>(P, T, r0t, c0, tid, hs);
  else
    phase_b<true>(P, T, r0t, c0, tid, hs);
  __syncthreads();

  // ---- Phase C: vertical windowed sums, row-streaming, 8 outputs/thread
  float lsum = 0.f;
  {
    const int x = tid & (TW - 1);
    const int r0 = (tid >> 5) * 8;  // 8 strips * 8 rows = 64
    float2 amu[8], asq[8];
#pragma unroll
    for (int o = 0; o < 8; ++o) {
      amu[o] = make_float2(0.f, 0.f);
      asq[o] = make_float2(0.f, 0.f);
    }
#pragma unroll
    for (int j = 0; j < 18; ++j) {
      const uint2 hv = hs[r0 + j][x];
      const float hcu = bf_lo(hv.x), hcv = bf_hi(hv.x);
      const float hc2u = bf_lo(hv.y), hc2v = bf_hi(hv.y);
#pragma unroll
      for (int o = 0; o < 8; ++o) {
        const int k = j - o;
        if (k >= 0 && k < 11) {
          const float w = GW[k];
          amu[o].x = fmaf(w, hcu, amu[o].x);
          amu[o].y = fmaf(w, hcv, amu[o].y);
          asq[o].x = fmaf(w, hc2u, asq[o].x);
          asq[o].y = fmaf(w, hc2v, asq[o].y);
        }
      }
    }
#pragma unroll
    for (int o = 0; o < 8; ++o) {
      const float cu = amu[o].x, cv = amu[o].y;
      const float cu2 = asq[o].x, cv2 = asq[o].y;
      const float cusq = cu * cu, cvsq = cv * cv;
      const float mu12 = 0.25f * (cusq - cvsq);       // mu1*mu2
      const float musq = 0.5f * (cusq + cvsq);        // mu1^2+mu2^2
      const float s12 = 0.25f * (cu2 - cv2);          // conv(p*t)
      const float ssq = 0.5f * (cu2 + cv2);           // s11+s22
      const float num = (2.f * mu12 + 1e-4f) * (2.f * (s12 - mu12) + 9e-4f);
      const float den = (musq + 1e-4f) * (ssq - musq + 9e-4f);
      lsum += num * __builtin_amdgcn_rcpf(den);
    }
  }

  // ---- Block reduce, one f64 atomic per block into per-channel bucket
#pragma unroll
  for (int off = 32; off > 0; off >>= 1) lsum += __shfl_down(lsum, off, 64);
  if ((tid & 63) == 0) wsum[tid >> 6] = lsum;
  __syncthreads();
  if (tid == 0) {
    const float bsum = wsum[0] + wsum[1] + wsum[2] + wsum[3];
    unsafeAtomicAdd(&ws[nc], (double)bsum);
  }
}

__global__ void ssim_fin(const double* __restrict__ ws,
                         float* __restrict__ out) {
  const int l = threadIdx.x;
  double v = (l < NCHAN) ? ws[l] : 0.0;
#pragma unroll
  for (int off = 32; off > 0; off >>= 1) v += __shfl_down(v, off, 64);
  if (l == 0) out[0] = (float)(1.0 - v / (double)(IMG * IMG * NCHAN));
}

extern "C" void kernel_launch(void* const* d_in, const int* in_sizes, int n_in,
                              void* d_out, int out_size, void* d_ws,
                              size_t ws_size, hipStream_t stream) {
  const float* pred = (const float*)d_in[0];
  const float* tgt = (const float*)d_in[1];
  double* ws = (double*)d_ws;

  (void)hipMemsetAsync(d_ws, 0, NCHAN * sizeof(double), stream);
  dim3 grid(IMG / TW, IMG / TH, NCHAN);
  ssim_main<<<grid, 256, 0, stream>>>(pred, tgt, ws);
  ssim_fin<<<1, 64, 0, stream>>>(ws, (float*)d_out);
}